// Round 8
// baseline (4315.179 us; speedup 1.0000x reference)
//
#include <hip/hip_runtime.h>
#include <stdint.h>

// Problem dims
#define BATCH 128
#define SEQ   512
#define DIN   256
#define HID   512
#define NWG   256    // 4 sets x 64 WGs (32 L0 + 32 L1); 1 WG/CU
#define TPB   256    // 4 waves = K-quarters; M = one 16-row tile per half-slot
#define NSLOT 513
#define OUTD  1275
#define HSLOT (BATCH * HID)

typedef __attribute__((ext_vector_type(8))) short bf16x8;
typedef __attribute__((ext_vector_type(4))) unsigned int uint4v;
typedef __attribute__((ext_vector_type(4))) float f32x4;

static __device__ __forceinline__ unsigned short f2bf(float f) {
  unsigned int u = __builtin_bit_cast(unsigned int, f);
  u += 0x7FFFu + ((u >> 16) & 1u);  // RNE
  return (unsigned short)(u >> 16);
}
static __device__ __forceinline__ float sigmoidf_fast(float v) {
  float e = __expf(-fabsf(v));
  float s = 1.0f / (1.0f + e);
  return v >= 0.0f ? s : 1.0f - s;
}
static __device__ __forceinline__ float tanhf_fast(float v) {
  float e = __expf(-2.0f * fabsf(v));
  float t = (1.0f - e) / (1.0f + e);
  return v >= 0.0f ? t : -t;
}

// Fine-grained (coherence-point) ops: sc0 sc1 bypass L1+L2 — zero cache
// maintenance in the steady-state loop (the R6 2.3x win).
static __device__ __forceinline__ void ldg_nc(bf16x8& d, const unsigned short* p) {
  asm volatile("global_load_dwordx4 %0, %1, off sc0 sc1" : "=v"(d) : "v"(p));
}
static __device__ __forceinline__ void ldg_nc_dw(unsigned int& d, const unsigned int* p) {
  asm volatile("global_load_dword %0, %1, off sc0 sc1" : "=v"(d) : "v"(p));
}
static __device__ __forceinline__ void stg_nc16(unsigned short* p, uint4v v) {
  asm volatile("global_store_dwordx4 %0, %1, off sc0 sc1" :: "v"(p), "v"(v) : "memory");
}
#define WAIT_TIE1(v) asm volatile("s_waitcnt vmcnt(0)" : "+v"(v) :: "memory")
#define WAIT_TIE4(A)                                                          \
  asm volatile("s_waitcnt vmcnt(0)"                                           \
               : "+v"((A)[0]), "+v"((A)[1]), "+v"((A)[2]), "+v"((A)[3])       \
               :: "memory")
#define WAIT_TIE6(A)                                                          \
  asm volatile("s_waitcnt vmcnt(0)"                                           \
               : "+v"((A)[0]), "+v"((A)[1]), "+v"((A)[2]), "+v"((A)[3]),      \
                 "+v"((A)[4]), "+v"((A)[5]) :: "memory")
#define WAIT_TIE8(A)                                                          \
  asm volatile("s_waitcnt vmcnt(0)"                                           \
               : "+v"((A)[0]), "+v"((A)[1]), "+v"((A)[2]), "+v"((A)[3]),      \
                 "+v"((A)[4]), "+v"((A)[5]), "+v"((A)[6]), "+v"((A)[7])       \
               :: "memory")

// x -> bf16 MFMA-fragment order: xb[(((p*8+mi)*8+kt)*64+lane)*8]
__global__ __launch_bounds__(256) void xprep(const float* __restrict__ x,
                                             unsigned short* __restrict__ xb) {
  int p = blockIdx.x;
  int lane = threadIdx.x & 63;
  int g4 = threadIdx.x >> 6;
  int c15 = lane & 15, q = lane >> 4;
  for (int g = 0; g < 16; ++g) {
    int idx = g * 4 + g4;  // (mi,kt)
    int mi = idx >> 3, kt = idx & 7;
    int row = mi * 16 + c15;
    const float* src = x + ((size_t)row * SEQ + p) * DIN + kt * 32 + q * 8;
    f32x4 a = *(const f32x4*)src;
    f32x4 b = *(const f32x4*)(src + 4);
    bf16x8 v;
    v[0] = (short)f2bf(a[0]); v[1] = (short)f2bf(a[1]);
    v[2] = (short)f2bf(a[2]); v[3] = (short)f2bf(a[3]);
    v[4] = (short)f2bf(b[0]); v[5] = (short)f2bf(b[1]);
    v[6] = (short)f2bf(b[2]); v[7] = (short)f2bf(b[3]);
    *(bf16x8*)&xb[((((size_t)p * 8 + mi) * 8 + kt) * 64 + lane) * 8] = v;
  }
}

// Persistent 2-layer LSTM, batch-split + latency-interleaved. 4 sets x 32 rows;
// each set = 64 WGs (32 L0 + 32 L1, 16 units/WG, weights in LDS frag layout).
// Each WG alternates two independent 16-row half-groups A/B per slot: while
// A's publish-ack/poll RTT is in flight, B computes (chain hidden). Sync per
// half-group: single relaxed fire-and-forget atomic counter; consumers poll
// one dword (sc0sc1). No fences, no cache maintenance, placement-independent.
template <bool USE_XB>
__global__ __launch_bounds__(TPB, 1) void lstm_persistent(
    const float* __restrict__ x, const unsigned short* __restrict__ xb,
    const float* __restrict__ W0, const float* __restrict__ b0,
    const float* __restrict__ W1, const float* __restrict__ b1,
    unsigned int* __restrict__ cnts, unsigned short* __restrict__ h0buf,
    unsigned short* __restrict__ h1buf, float* __restrict__ h1fin)
{
  __shared__ unsigned short sWf[4 * 32 * 64 * 8];  // 128 KB B-frags [ct][kt][lane][8]
  __shared__ float red[4 * 16 * 66];               // 16.9 KB single-pass partials
  __shared__ unsigned short stg2[2][16 * 16];      // 2 x 512 B h stage (A/B)

  const int tid  = threadIdx.x;
  const int wgid = blockIdx.x;
  const int set  = wgid >> 6;          // batch rows [32*set, 32*set+32)
  const int r    = wgid & 63;
  const bool isA = (r < 32);           // role: layer0 / layer1
  const int unit0 = (isA ? r : r - 32) << 4;  // 16 units per WG
  const int lane = tid & 63;
  const int kq   = tid >> 6;           // wave = K-quarter 0..3
  const int c15  = lane & 15;
  const int q    = lane >> 4;
  const int KT   = isA ? 24 : 32;
  const int ktu  = unit0 >> 5;         // publish frag coords
  const int qbase = (unit0 >> 3) & 3;

  // ---- one-time: weights -> LDS fragment layout; col c = u_local*4 + gate ----
  {
    const float* W = isA ? W0 : W1;
    for (int f = tid; f < 4 * KT * 64; f += TPB) {
      int ct = f / (KT * 64);
      int rem = f - ct * (KT * 64);
      int kt = rem >> 6, ln = rem & 63;
      int qq = ln >> 4, cc = ln & 15;
      int gcol = (cc & 3) * HID + unit0 + ct * 4 + (cc >> 2);
      int kbase = kt * 32 + qq * 8;
      bf16x8 v;
#pragma unroll
      for (int j = 0; j < 8; ++j)
        v[j] = (short)f2bf(W[(size_t)(kbase + j) * 2048 + gcol]);
      *(bf16x8*)&sWf[(size_t)f * 8] = v;
    }
  }

  // gate thread = (row 0..15, unit 0..15); col in red = u*4+gate
  const int grow = tid >> 4, gu = tid & 15;
  float bias_g[4];
  {
    const float* bv = isA ? b0 : b1;
#pragma unroll
    for (int gt = 0; gt < 4; ++gt)
      bias_g[gt] = bv[gt * HID + unit0 + gu];
  }
  float cst[2] = {0.f, 0.f};  // cell state per half-group
  __syncthreads();

  unsigned int* cntH[2] = {cnts + (set * 2 + 0) * 32, cnts + (set * 2 + 1) * 32};

#define BFRAG(ct, kt) (*(const bf16x8*)&sWf[((((ct) * KT + (kt)) << 6) + lane) << 3])

  for (int p = 0; p < NSLOT; ++p) {
    const unsigned short* h0rd = h0buf + ((p + 1) & 1) * HSLOT;
    unsigned short* h0wr       = h0buf + (p & 1) * HSLOT;
    const unsigned short* h1rd = h1buf + (p & 1) * HSLOT;
    unsigned short* h1wr       = h1buf + ((p + 1) & 1) * HSLOT;
    const bool active = isA ? (p < SEQ) : (p >= 1);
    const unsigned int target = (unsigned int)(64 * p);

#pragma unroll
    for (int half = 0; half < 2; ++half) {
      const int miG = set * 2 + half;  // this half-group's 16-row M-tile

      f32x4 acc[4];
#pragma unroll
      for (int ct = 0; ct < 4; ++ct) acc[ct] = (f32x4){0.f, 0.f, 0.f, 0.f};

      // ---- pre-poll: L0 x-part of my K-quarter (cached loads, overlaps RTT) ----
      if (isA && active) {
        int ktlo = kq * 6, kthi = ktlo + 6;
        for (int kt = ktlo; kt < kthi && kt < 8; ++kt) {
          bf16x8 ax;
          if (USE_XB) {
            ax = *(const bf16x8*)&xb[((((size_t)p * 8 + miG) * 8 + kt) * 64 + lane) * 8];
          } else {
            const float* xp0 = x + (((size_t)(miG * 16 + c15)) * SEQ + p) * DIN + kt * 32 + q * 8;
            f32x4 a = *(const f32x4*)xp0;
            f32x4 b = *(const f32x4*)(xp0 + 4);
            ax[0] = (short)f2bf(a[0]); ax[1] = (short)f2bf(a[1]);
            ax[2] = (short)f2bf(a[2]); ax[3] = (short)f2bf(a[3]);
            ax[4] = (short)f2bf(b[0]); ax[5] = (short)f2bf(b[1]);
            ax[6] = (short)f2bf(b[2]); ax[7] = (short)f2bf(b[3]);
          }
#pragma unroll
          for (int ct = 0; ct < 4; ++ct)
            acc[ct] = __builtin_amdgcn_mfma_f32_16x16x32_bf16(ax, BFRAG(ct, kt), acc[ct], 0, 0, 0);
        }
      }

      // ---- wait: this half's slot p-1 fully published (single-dword poll) ----
      if (tid == 0 && p > 0) {
        const unsigned int* cp = cntH[half];
        for (;;) {
          unsigned int v;
          ldg_nc_dw(v, cp);
          WAIT_TIE1(v);
          if (v >= target) break;
          __builtin_amdgcn_s_sleep(1);
        }
      }
      __syncthreads();

      // ---- dependent K-part: fine-grained h loads, partial-K MFMA ----
      if (active) {
        if (isA) {
          if (kq == 1) {         // kt 8..11 -> h0 frags 0..3
            bf16x8 ah[4];
#pragma unroll
            for (int i = 0; i < 4; ++i)
              ldg_nc(ah[i], h0rd + ((size_t)(miG * 16 + i) * 64 + lane) * 8);
            WAIT_TIE4(ah);
#pragma unroll
            for (int i = 0; i < 4; ++i)
#pragma unroll
              for (int ct = 0; ct < 4; ++ct)
                acc[ct] = __builtin_amdgcn_mfma_f32_16x16x32_bf16(ah[i], BFRAG(ct, 8 + i), acc[ct], 0, 0, 0);
          } else if (kq >= 2) {  // kt 12..17 / 18..23 -> h0 frags 4..9 / 10..15
            bf16x8 ah[6];
            int kt0 = kq * 6;
#pragma unroll
            for (int i = 0; i < 6; ++i)
              ldg_nc(ah[i], h0rd + ((size_t)(miG * 16 + (kt0 - 8 + i)) * 64 + lane) * 8);
            WAIT_TIE6(ah);
#pragma unroll
            for (int i = 0; i < 6; ++i)
#pragma unroll
              for (int ct = 0; ct < 4; ++ct)
                acc[ct] = __builtin_amdgcn_mfma_f32_16x16x32_bf16(ah[i], BFRAG(ct, kt0 + i), acc[ct], 0, 0, 0);
          }
        } else {
          bf16x8 ah[8];
          const unsigned short* src = (kq < 2) ? h0rd : h1rd;
          int ktf0 = (kq < 2) ? kq * 8 : (kq - 2) * 8;
#pragma unroll
          for (int i = 0; i < 8; ++i)
            ldg_nc(ah[i], src + ((size_t)(miG * 16 + ktf0 + i) * 64 + lane) * 8);
          WAIT_TIE8(ah);
#pragma unroll
          for (int i = 0; i < 8; ++i)
#pragma unroll
            for (int ct = 0; ct < 4; ++ct)
              acc[ct] = __builtin_amdgcn_mfma_f32_16x16x32_bf16(ah[i], BFRAG(ct, kq * 8 + i), acc[ct], 0, 0, 0);
        }
      }

      // ---- single-pass cross-wave K-reduce (red[kq][row][66]) ----
      if (active) {
#pragma unroll
        for (int ct = 0; ct < 4; ++ct)
#pragma unroll
          for (int rr = 0; rr < 4; ++rr)
            red[(kq * 16 + q * 4 + rr) * 66 + ct * 16 + c15] = acc[ct][rr];
      }
      __syncthreads();

      // ---- gates: all 256 threads, thread = (row, unit) ----
      if (active) {
        float z[4];
#pragma unroll
        for (int gt = 0; gt < 4; ++gt) {
          float s = bias_g[gt];
#pragma unroll
          for (int k2 = 0; k2 < 4; ++k2)
            s += red[(k2 * 16 + grow) * 66 + gu * 4 + gt];
          z[gt] = s;
        }
        float cn = sigmoidf_fast(z[1]) * cst[half] + sigmoidf_fast(z[0]) * tanhf_fast(z[2]);
        cst[half] = cn;
        float hn = sigmoidf_fast(z[3]) * tanhf_fast(cn);
        stg2[half][grow * 16 + gu] = f2bf(hn);
        if (!isA && p == NSLOT - 1)
          h1fin[(size_t)(set * 32 + half * 16 + grow) * HID + unit0 + gu] = hn;
      }
      __syncthreads();

      // ---- wave0: publish (frag layout, sc0sc1) + drain + counter; rest roll on ----
      if (kq == 0) {
        if (active && lane < 32) {
          int row = lane >> 1, qq2 = lane & 1;
          uint4v v = *(const uint4v*)&stg2[half][row * 16 + qq2 * 8];
          unsigned short* dst = (isA ? h0wr : h1wr) +
              ((size_t)(miG * 16 + ktu) * 64 + (qbase + qq2) * 16 + row) * 8;
          stg_nc16(dst, v);
        }
        asm volatile("s_waitcnt vmcnt(0)" ::: "memory");  // stores acked at fabric
        if (tid == 0)
          (void)__hip_atomic_fetch_add(cntH[half], 1u, __ATOMIC_RELAXED,
                                       __HIP_MEMORY_SCOPE_AGENT);
      }
      // no trailing barrier: next half's post-poll __syncthreads rejoins waves
    }
  }
#undef BFRAG
}

__global__ __launch_bounds__(256) void proj_kernel(
    const float* __restrict__ h1, const float* __restrict__ Wp,
    const float* __restrict__ bp, float* __restrict__ out)
{
  int o = blockIdx.x * 256 + threadIdx.x;
  int b = blockIdx.y;
  if (o >= OUTD) return;
  const float* hr = h1 + (size_t)b * HID;
  float acc = bp[o];
#pragma unroll 8
  for (int k = 0; k < HID; ++k)
    acc = fmaf(hr[k], Wp[(size_t)k * OUTD + o], acc);
  out[(size_t)b * OUTD + o] = acc;
}

extern "C" void kernel_launch(void* const* d_in, const int* in_sizes, int n_in,
                              void* d_out, int out_size, void* d_ws, size_t ws_size,
                              hipStream_t stream) {
  const float* x  = (const float*)d_in[0];
  const float* W0 = (const float*)d_in[1];
  const float* b0 = (const float*)d_in[2];
  const float* W1 = (const float*)d_in[3];
  const float* b1 = (const float*)d_in[4];
  const float* Wp = (const float*)d_in[5];
  const float* bp = (const float*)d_in[6];
  float* out = (float*)d_out;

  char* ws = (char*)d_ws;
  unsigned int* cnts  = (unsigned int*)ws;                        // 8 ctrs, 128-B spaced
  unsigned short* h0b = (unsigned short*)(ws + 4096);             // 256 KB (2 slots)
  unsigned short* h1b = (unsigned short*)(ws + 4096 + 262144);    // 256 KB
  float* h1fin        = (float*)(ws + 4096 + 2 * 262144);         // 256 KB
  unsigned short* xbp = (unsigned short*)(ws + 4096 + 3 * 262144);// 32 MB
  const size_t need_xb = 4096 + 3 * 262144 + (size_t)SEQ * BATCH * DIN * 2;
  const bool use_xb = (ws_size >= need_xb);

  hipMemsetAsync(d_ws, 0, 4096 + 2 * 262144, stream);
  if (use_xb) {
    hipLaunchKernelGGL(xprep, dim3(SEQ), dim3(256), 0, stream, x, xbp);
    hipLaunchKernelGGL(lstm_persistent<true>, dim3(NWG), dim3(TPB), 0, stream,
                       x, xbp, W0, b0, W1, b1, cnts, h0b, h1b, h1fin);
  } else {
    hipLaunchKernelGGL(lstm_persistent<false>, dim3(NWG), dim3(TPB), 0, stream,
                       x, xbp, W0, b0, W1, b1, cnts, h0b, h1b, h1fin);
  }
  hipLaunchKernelGGL(proj_kernel, dim3((OUTD + 255) / 256, BATCH), dim3(256), 0, stream,
                     h1fin, Wp, bp, out);
}